// Round 7
// baseline (546.651 us; speedup 1.0000x reference)
//
#include <hip/hip_runtime.h>
#include <cstdint>

// Problem constants (from reference)
constexpr int G = 4, N = 50000, E = 800000;
constexpr int FIN = 64, HID = 128, FOUT = 64;
constexpr int NB = (N + 1023) / 1024;  // scan blocks per graph = 49

// Radix CSR-build parameters (R9)
constexpr int PB = 64;               // partition blocks per graph
constexpr int CP = E / PB;           // 12500 edges per partition chunk (exact)
constexpr int NBK = (N + 255) / 256; // 196 dst-buckets of 256 nodes

typedef unsigned short ushort;
typedef _Float16 f16;

__device__ __forceinline__ ushort f2h(float f) {  // v_cvt_f16_f32 (RNE)
  f16 h = (f16)f;
  return __builtin_bit_cast(ushort, h);
}
__device__ __forceinline__ float h2f(ushort u) {  // v_cvt_f32_f16
  f16 h = __builtin_bit_cast(f16, u);
  return (float)h;
}

// XCD-confined swizzle: block b -> XCD (b&7), 2 XCDs per graph.
// Requires G*N/4 = 50000 blocks; per graph 12500 chunks of 4 nodes.
__device__ __forceinline__ void xcd_map(int b, int& g, int& chunk) {
  int xcd = b & 7;
  int sub = b >> 3;  // 0..6249
  g = xcd >> 1;
  chunk = (xcd & 1) * 6250 + sub;  // 0..12499
}

// ---------------- fp32 -> fp16 conversion of x, PRE-SCALED by dinv ----------------
// R7: fp16 halves gather bytes + L2 working set. R10: also fold dinv[s] into
// the stored row (xh[s] = dinv[s]*x[s]) so the aggregation needs NO per-edge
// dinv gather -- Z = dinv[d] * sum_{s in N(d)+self} xh[s]. Runs AFTER the scans.
__global__ void k_x2h(const float4* __restrict__ X, const float* __restrict__ dinv,
                      ushort4* __restrict__ Xh, int n4) {
  int i = blockIdx.x * blockDim.x + threadIdx.x;
  if (i >= n4) return;
  float sc = dinv[i >> 4];  // 16 float4 per 64-wide row; same dinv for all 16
  float4 v = X[i];
  ushort4 o = {f2h(sc * v.x), f2h(sc * v.y), f2h(sc * v.z), f2h(sc * v.w)};
  Xh[i] = o;
}

// ---------------- CSR build: two-pass radix partition by dst (R9) ----------------
// R8 post-mortem: scattered SUB-LINE stores cost like atomics (8x write amp).
// All global writes made (near-)line-contiguous via 196-bucket dst partition.

// PH[g][k][pb]: bucket-k count of partition chunk pb
__global__ __launch_bounds__(256) void k_phist(const int* __restrict__ ei,
                                               int* __restrict__ PH) {
  __shared__ int h[NBK];
  int pb = blockIdx.x, g = blockIdx.y;
  for (int i = threadIdx.x; i < NBK; i += 256) h[i] = 0;
  __syncthreads();
  const int4* dst4 = (const int4*)(ei + (size_t)g * 2 * E + E + (size_t)pb * CP);
  for (int i = threadIdx.x; i < CP / 4; i += 256) {
    int4 d = dst4[i];
    atomicAdd(&h[d.x >> 8], 1);
    atomicAdd(&h[d.y >> 8], 1);
    atomicAdd(&h[d.z >> 8], 1);
    atomicAdd(&h[d.w >> 8], 1);
  }
  __syncthreads();
  for (int i = threadIdx.x; i < NBK; i += 256)
    PH[((size_t)g * NBK + i) * PB + pb] = h[i];
}

// scan PH -> POFF[g][k][pb] (segment base in pairs) and BB[g][k] (bucket base)
__global__ void k_pscan(const int* __restrict__ PH, int* __restrict__ POFF,
                        int* __restrict__ BB) {
  int g = blockIdx.x, k = threadIdx.x;  // 256 threads, k < NBK active
  int tot = 0;
  if (k < NBK) {
#pragma unroll 8
    for (int pb = 0; pb < PB; ++pb) tot += PH[((size_t)g * NBK + k) * PB + pb];
  }
  __shared__ int sm[256];
  sm[k] = tot;
  __syncthreads();
  for (int off = 1; off < 256; off <<= 1) {
    int v = (k >= off) ? sm[k - off] : 0;
    __syncthreads();
    sm[k] += v;
    __syncthreads();
  }
  int excl = sm[k] - tot;
  if (k < NBK) {
    BB[g * (NBK + 1) + k] = excl;
    if (k == NBK - 1) BB[g * (NBK + 1) + NBK] = excl + tot;  // == E
    int run = excl;
#pragma unroll 8
    for (int pb = 0; pb < PB; ++pb) {
      POFF[((size_t)g * NBK + k) * PB + pb] = run;
      run += PH[((size_t)g * NBK + k) * PB + pb];
    }
  }
}

// partition: write packed (src, dst&255) into bucket-major pairs array
__global__ __launch_bounds__(256) void k_part(const int* __restrict__ ei,
                                              const int* __restrict__ POFF,
                                              unsigned* __restrict__ pairs) {
  __shared__ int off[NBK];
  __shared__ int rk[NBK];
  int pb = blockIdx.x, g = blockIdx.y;
  for (int i = threadIdx.x; i < NBK; i += 256) {
    off[i] = POFF[((size_t)g * NBK + i) * PB + pb];
    rk[i] = 0;
  }
  __syncthreads();
  const int* base = ei + (size_t)g * 2 * E + (size_t)pb * CP;
  const int4* s4 = (const int4*)base;
  const int4* d4 = (const int4*)(base + E);
  unsigned* pg = pairs + (size_t)g * E;
  for (int i = threadIdx.x; i < CP / 4; i += 256) {
    int4 s = s4[i], d = d4[i];
    int sv[4] = {s.x, s.y, s.z, s.w};
    int dv[4] = {d.x, d.y, d.z, d.w};
#pragma unroll
    for (int k = 0; k < 4; ++k) {
      int b = dv[k] >> 8;
      int r = atomicAdd(&rk[b], 1);
      pg[off[b] + r] = (unsigned)sv[k] | ((unsigned)(dv[k] & 255) << 16);
    }
  }
}

// per-bucket exact node counts -> cnt (contiguous writes)
__global__ __launch_bounds__(256) void k_bcnt(const unsigned* __restrict__ pairs,
                                              const int* __restrict__ BB,
                                              int* __restrict__ cnt) {
  __shared__ int h[256];
  int k = blockIdx.x, g = blockIdx.y;
  h[threadIdx.x] = 0;
  __syncthreads();
  int lo = BB[g * (NBK + 1) + k], hi = BB[g * (NBK + 1) + k + 1];
  const unsigned* pg = pairs + (size_t)g * E;
  for (int i = lo + (int)threadIdx.x; i < hi; i += 256)
    atomicAdd(&h[(pg[i] >> 16) & 255], 1);
  __syncthreads();
  int n0 = k << 8;
  int nn = min(256, N - n0);
  if ((int)threadIdx.x < nn) cnt[g * N + n0 + threadIdx.x] = h[threadIdx.x];
}

// place srcs into col; scatter confined to the bucket's ~16KB col window
__global__ __launch_bounds__(256) void k_place(const unsigned* __restrict__ pairs,
                                               const int* __restrict__ BB,
                                               const int* __restrict__ rowptr,
                                               int* __restrict__ col) {
  __shared__ int rp[256];
  __shared__ int rk[256];
  int k = blockIdx.x, g = blockIdx.y;
  int n0 = k << 8;
  int nn = min(256, N - n0);
  if ((int)threadIdx.x < nn) rp[threadIdx.x] = rowptr[g * (N + 1) + n0 + threadIdx.x];
  rk[threadIdx.x] = 0;
  __syncthreads();
  int lo = BB[g * (NBK + 1) + k], hi = BB[g * (NBK + 1) + k + 1];
  const unsigned* pg = pairs + (size_t)g * E;
  int* cg = col + (size_t)g * E;
  for (int i = lo + (int)threadIdx.x; i < hi; i += 256) {
    unsigned p = pg[i];
    int dl = (p >> 16) & 255;
    int r = atomicAdd(&rk[dl], 1);
    cg[rp[dl] + r] = (int)(p & 0xffffu);
  }
}

// ---- 3-kernel exclusive scan of cnt -> rowptr (per graph) ----
__global__ void k_scan_partial(const int* __restrict__ cnt, int* __restrict__ part) {
  int g = blockIdx.y, b = blockIdx.x, tid = threadIdx.x;
  int base = b * 1024 + tid * 4;
  int s = 0;
#pragma unroll
  for (int k = 0; k < 4; ++k) {
    int i = base + k;
    if (i < N) s += cnt[g * N + i];
  }
  __shared__ int sm[256];
  sm[tid] = s;
  __syncthreads();
  for (int off = 128; off > 0; off >>= 1) {
    if (tid < off) sm[tid] += sm[tid + off];
    __syncthreads();
  }
  if (tid == 0) part[g * NB + b] = sm[0];
}

__global__ void k_scan_mid(int* __restrict__ part, int* __restrict__ rowptr) {
  int g = blockIdx.x;
  if (threadIdx.x != 0) return;
  int run = 0;
  for (int b = 0; b < NB; ++b) {
    int t = part[g * NB + b];
    part[g * NB + b] = run;
    run += t;
  }
  rowptr[g * (N + 1) + N] = run;  // == E
}

// final scan + fused dinv computation
__global__ void k_scan_final(const int* __restrict__ cnt, const int* __restrict__ part,
                             int* __restrict__ rowptr, float* __restrict__ dinv) {
  int g = blockIdx.y, b = blockIdx.x, tid = threadIdx.x;
  int base = b * 1024 + tid * 4;
  int c[4];
  int s = 0;
#pragma unroll
  for (int k = 0; k < 4; ++k) {
    int i = base + k;
    c[k] = (i < N) ? cnt[g * N + i] : 0;
    s += c[k];
  }
  __shared__ int sm[256];
  sm[tid] = s;
  __syncthreads();
  for (int off = 1; off < 256; off <<= 1) {
    int v = (tid >= off) ? sm[tid - off] : 0;
    __syncthreads();
    sm[tid] += v;
    __syncthreads();
  }
  int excl = sm[tid] - s + part[g * NB + b];
#pragma unroll
  for (int k = 0; k < 4; ++k) {
    int i = base + k;
    if (i < N) {
      rowptr[g * (N + 1) + i] = excl;
      dinv[g * N + i] = rsqrtf((float)(c[k] + 1));  // +1 self loop
    }
    excl += c[k];
  }
}

// ---------------- LDS-staged GEMM: columns across waves, lane = row ----------------
// Block = 256 threads = 4 waves, covers 64 rows. X tile staged ONCE in LDS
// (padded row stride K+1 -> (lane+k)%32 bank map, 2 lanes/bank = free).
// Wave w computes columns [w*F/4, (w+1)*F/4) for all 64 rows.
// c0 forced into an SGPR via readfirstlane so the W address chain is provably
// scalar -> batched s_load through the constant cache on the scalar pipe
// (R5 bug: threadIdx-derived c0 failed divergence analysis -> per-lane
// global_load_dword, VMEM-issue bound, 230 us).
template <int K, int F, bool PRESCALE, bool BIASELU, bool OUTH>
__global__ __launch_bounds__(256) void k_gemm_lds(const float* __restrict__ X,
                                                  const float* __restrict__ W,
                                                  const float* __restrict__ dinv,
                                                  const float* __restrict__ bias,
                                                  void* __restrict__ Hout) {
  constexpr int CH = F / 4;  // columns per wave (32 or 16)
  constexpr int PK = K + 1;  // padded LDS row stride
  __shared__ float xs[64 * PK];
  int g = blockIdx.y;
  int R0 = blockIdx.x * 64;
  // stage 64 rows (coalesced global read, conflict-free LDS write)
  for (int idx = threadIdx.x; idx < 64 * K; idx += 256) {
    int r = idx / K, k = idx - r * K;
    int row = R0 + r;
    xs[r * PK + k] = (row < N) ? X[((size_t)g * N + row) * K + k] : 0.f;
  }
  __syncthreads();
  int wv = threadIdx.x >> 6;
  int lane = threadIdx.x & 63;
  int c0 = __builtin_amdgcn_readfirstlane(wv * CH);  // SGPR column base
  const float* Wg = W + (size_t)g * K * F;
  const float* xrow = &xs[lane * PK];
  float acc[CH];
#pragma unroll
  for (int c = 0; c < CH; ++c) acc[c] = 0.f;
#pragma unroll 4
  for (int k = 0; k < K; ++k) {
    float xv = xrow[k];
#pragma unroll
    for (int c = 0; c < CH; ++c)
      acc[c] = fmaf(xv, Wg[(size_t)k * F + c0 + c], acc[c]);
  }
  int row = R0 + lane;
  if (row >= N) return;
  if constexpr (PRESCALE) {
    float sc = dinv[g * N + row];
#pragma unroll
    for (int c = 0; c < CH; ++c) acc[c] *= sc;
  }
  if constexpr (BIASELU) {
#pragma unroll
    for (int c = 0; c < CH; ++c) {
      float v = acc[c] + bias[g * F + c0 + c];
      acc[c] = v > 0.f ? v : expm1f(v);
    }
  }
  if constexpr (OUTH) {  // fp16 out (4x finer mantissa than bf16, same bytes)
    ushort* opb = (ushort*)Hout + ((size_t)g * N + row) * F + c0;
#pragma unroll
    for (int c4 = 0; c4 < CH; c4 += 4) {
      ushort4 o = {f2h(acc[c4]), f2h(acc[c4 + 1]), f2h(acc[c4 + 2]),
                   f2h(acc[c4 + 3])};
      *(ushort4*)(opb + c4) = o;
    }
  } else {
    float* op = (float*)Hout + ((size_t)g * N + row) * F + c0;
#pragma unroll
    for (int c4 = 0; c4 < CH; c4 += 4) {
      float4 o = {acc[c4], acc[c4 + 1], acc[c4 + 2], acc[c4 + 3]};
      *(float4*)(op + c4) = o;
    }
  }
}

// ---------------- aggregate (shared structure, R11) ----------------
// R10 post-mortem: de-shuffled agg stayed ~90us with VALUBusy 28%, HBM 23%,
// FETCH flat -> bound by per-VMEM-instruction overhead (17.9 cyc/gather/CU),
// not bytes. R11: quarter-wave gathers -- 16 lanes x ushort4 = 4 edges per
// VMEM instruction (4x fewer instructions, same bytes). Lane l covers
// features (l&15)*4..+3 of edge j+4t+(l>>4); row index chosen from 4 s_load'ed
// col values by a 2-level cndmask tree; 32-bit voffset off SGPR base.
// Epilogue: shfl_xor(16)+shfl_xor(32) sums the quarters; quarter 0 writes.
template <int F>
__device__ __forceinline__ void agg_core(const ushort* __restrict__ hb,
                                         const int* __restrict__ cl, int rs, int re,
                                         int q, int fo, float& ax, float& ay,
                                         float& az, float& aw) {
  int j = rs;
  for (; j + 16 <= re; j += 16) {
    int s[16];
#pragma unroll
    for (int k = 0; k < 16; ++k) s[k] = cl[j + k];  // uniform -> s_load
#pragma unroll
    for (int t = 0; t < 4; ++t) {
      int r01 = (q & 1) ? s[4 * t + 1] : s[4 * t + 0];
      int r23 = (q & 1) ? s[4 * t + 3] : s[4 * t + 2];
      int row = (q & 2) ? r23 : r01;
      ushort4 v = *(const ushort4*)(hb + (row << 6) + fo);
      ax += h2f(v.x);
      ay += h2f(v.y);
      az += h2f(v.z);
      aw += h2f(v.w);
    }
  }
  for (; j < re; j += 4) {  // wave-uniform masked tail groups
    int m = re - j;
    int s0 = cl[j];
    int s1 = (m > 1) ? cl[j + 1] : s0;
    int s2 = (m > 2) ? cl[j + 2] : s0;
    int s3 = (m > 3) ? cl[j + 3] : s0;
    int r01 = (q & 1) ? s1 : s0;
    int r23 = (q & 1) ? s3 : s2;
    int row = (q & 2) ? r23 : r01;
    ushort4 v = *(const ushort4*)(hb + (row << 6) + fo);
    if (q < m) {
      ax += h2f(v.x);
      ay += h2f(v.y);
      az += h2f(v.z);
      aw += h2f(v.w);
    }
  }
  ax += __shfl_xor(ax, 16);
  ay += __shfl_xor(ay, 16);
  az += __shfl_xor(az, 16);
  aw += __shfl_xor(aw, 16);
  ax += __shfl_xor(ax, 32);
  ay += __shfl_xor(ay, 32);
  az += __shfl_xor(az, 32);
  aw += __shfl_xor(aw, 32);
}

// layer 1: Z = dinv[d] * sum xh[s] (xh pre-scaled by dinv[s])
template <int F>
__global__ __launch_bounds__(256) void k_agg_in(const ushort* __restrict__ Xh,
                                                const int* __restrict__ rowptr,
                                                const int* __restrict__ col,
                                                const float* __restrict__ dinv,
                                                float* __restrict__ Z) {
  int g, chunk;
  xcd_map(blockIdx.x, g, chunk);
  int d = __builtin_amdgcn_readfirstlane(chunk * 4 + (threadIdx.x >> 6));
  int lane = threadIdx.x & 63;
  int q = lane >> 4;
  int fo = (lane & 15) * 4;
  const ushort* hb = Xh + (size_t)g * N * F;
  const int* cl = col + (size_t)g * E;
  int rs = rowptr[g * (N + 1) + d];
  int re = rowptr[g * (N + 1) + d + 1];
  float ax = 0.f, ay = 0.f, az = 0.f, aw = 0.f;
  {  // self loop (pre-scaled row), added by quarter 0 only
    ushort4 v = *(const ushort4*)(hb + (d << 6) + fo);
    if (q == 0) {
      ax = h2f(v.x);
      ay = h2f(v.y);
      az = h2f(v.z);
      aw = h2f(v.w);
    }
  }
  agg_core<F>(hb, cl, rs, re, q, fo, ax, ay, az, aw);
  if (q == 0) {
    float dd = dinv[g * N + d];
    float4 o = {ax * dd, ay * dd, az * dd, aw * dd};
    *(float4*)(Z + ((size_t)g * N + d) * F + fo) = o;
  }
}

// layer 2: out = ELU(dinv[d]*(sum h2s) + b); h2s pre-scaled by dinv[s]
template <int F>
__global__ __launch_bounds__(256) void k_agg_out(const ushort* __restrict__ Hsrc,
                                                 const int* __restrict__ rowptr,
                                                 const int* __restrict__ col,
                                                 const float* __restrict__ dinv,
                                                 const float* __restrict__ bias,
                                                 float* __restrict__ out) {
  int g, chunk;
  xcd_map(blockIdx.x, g, chunk);
  int d = __builtin_amdgcn_readfirstlane(chunk * 4 + (threadIdx.x >> 6));
  int lane = threadIdx.x & 63;
  int q = lane >> 4;
  int fo = (lane & 15) * 4;
  const ushort* hb = Hsrc + (size_t)g * N * F;
  const int* cl = col + (size_t)g * E;
  int rs = rowptr[g * (N + 1) + d];
  int re = rowptr[g * (N + 1) + d + 1];
  float ax = 0.f, ay = 0.f, az = 0.f, aw = 0.f;
  {  // self loop
    ushort4 v = *(const ushort4*)(hb + (d << 6) + fo);
    if (q == 0) {
      ax = h2f(v.x);
      ay = h2f(v.y);
      az = h2f(v.z);
      aw = h2f(v.w);
    }
  }
  agg_core<F>(hb, cl, rs, re, q, fo, ax, ay, az, aw);
  if (q == 0) {
    float dd = dinv[g * N + d];
    float4 b = *(const float4*)(bias + g * F + fo);
    float px = ax * dd + b.x, py = ay * dd + b.y;
    float pz = az * dd + b.z, pw = aw * dd + b.w;
    px = px > 0.f ? px : expm1f(px);
    py = py > 0.f ? py : expm1f(py);
    pz = pz > 0.f ? pz : expm1f(pz);
    pw = pw > 0.f ? pw : expm1f(pw);
    float4 o = {px, py, pz, pw};
    *(float4*)(out + ((size_t)g * N + d) * F + fo) = o;
  }
}

extern "C" void kernel_launch(void* const* d_in, const int* in_sizes, int n_in,
                              void* d_out, int out_size, void* d_ws, size_t ws_size,
                              hipStream_t stream) {
  const float* x = (const float*)d_in[0];
  const int* ei = (const int*)d_in[1];
  const float* W1 = (const float*)d_in[2];
  const float* b1 = (const float*)d_in[3];
  const float* W2 = (const float*)d_in[4];
  const float* b2 = (const float*)d_in[5];
  float* out = (float*)d_out;

  // Workspace carve-up (~169 MB; all radix/fp16 scratch aliased onto h1)
  char* p = (char*)d_ws;
  auto alloc = [&](size_t bytes) {
    char* r = p;
    p += (bytes + 255) & ~(size_t)255;
    return r;
  };
  int* cnt = (int*)alloc(sizeof(int) * G * N);
  int* rowptr = (int*)alloc(sizeof(int) * G * (N + 1));
  int* part = (int*)alloc(sizeof(int) * G * NB);
  float* dinv = (float*)alloc(sizeof(float) * G * N);
  int* col = (int*)alloc(sizeof(int) * (size_t)G * E);             // 12.8 MB
  float* z = (float*)alloc(sizeof(float) * (size_t)G * N * FIN);   // 51.2 MB
  float* h1 = (float*)alloc(sizeof(float) * (size_t)G * N * HID);  // 102.4 MB
  ushort* h2s = (ushort*)z;  // fp16, 25.6 MB; reuses z (dead after gemm1)
  // Radix + fp16-x scratch aliased into h1 (all dead before gemm1 writes h1):
  unsigned* pairs = (unsigned*)h1;                         // 12.8 MB
  int* PH = (int*)((char*)h1 + ((size_t)13 << 20));        // G*NBK*PB*4 = 200KB
  int* POFF = (int*)((char*)h1 + ((size_t)14 << 20));      // 200KB
  int* BB = (int*)((char*)h1 + ((size_t)15 << 20));        // G*(NBK+1)*4 = 3.2KB
  ushort* xh = (ushort*)((char*)h1 + ((size_t)32 << 20));  // fp16 x, 25.6 MB

  // 1. CSR build via two-pass radix partition (line-contiguous writes only)
  k_phist<<<dim3(PB, G), 256, 0, stream>>>(ei, PH);
  k_pscan<<<G, 256, 0, stream>>>(PH, POFF, BB);
  k_part<<<dim3(PB, G), 256, 0, stream>>>(ei, POFF, pairs);
  k_bcnt<<<dim3(NBK, G), 256, 0, stream>>>(pairs, BB, cnt);
  dim3 sg(NB, G);
  k_scan_partial<<<sg, 256, 0, stream>>>(cnt, part);
  k_scan_mid<<<G, 64, 0, stream>>>(part, rowptr);
  k_scan_final<<<sg, 256, 0, stream>>>(cnt, part, rowptr, dinv);
  k_place<<<dim3(NBK, G), 256, 0, stream>>>(pairs, BB, rowptr, col);

  // 2. x -> fp16 pre-scaled by dinv (after scans; removes per-edge dinv work)
  k_x2h<<<(G * N * FIN / 4 + 255) / 256, 256, 0, stream>>>(
      (const float4*)x, dinv, (ushort4*)xh, G * N * FIN / 4);

  // 3. layer 1: aggregate-first (quarter-wave fp16 gathers), then LDS-GEMM+bias+ELU
  k_agg_in<FIN><<<(G * N) / 4, 256, 0, stream>>>(xh, rowptr, col, dinv, z);
  dim3 gg((N + 63) / 64, G);
  k_gemm_lds<FIN, HID, false, true, false>
      <<<gg, 256, 0, stream>>>(z, W1, nullptr, b1, h1);

  // 4. layer 2: transform-first 128->64 (pre-scaled, fp16 out), then aggregate
  k_gemm_lds<HID, FOUT, true, false, true>
      <<<gg, 256, 0, stream>>>(h1, W2, dinv, nullptr, h2s);
  k_agg_out<FOUT><<<(G * N) / 4, 256, 0, stream>>>(h2s, rowptr, col, dinv, b2, out);
}

// Round 8
// 516.800 us; speedup vs baseline: 1.0578x; 1.0578x over previous
//
#include <hip/hip_runtime.h>
#include <cstdint>

// Problem constants (from reference)
constexpr int G = 4, N = 50000, E = 800000;
constexpr int FIN = 64, HID = 128, FOUT = 64;
constexpr int NB = (N + 1023) / 1024;  // scan blocks per graph = 49

// Radix CSR-build parameters (R9)
constexpr int PB = 64;               // partition blocks per graph
constexpr int CP = E / PB;           // 12500 edges per partition chunk (exact)
constexpr int NBK = (N + 255) / 256; // 196 dst-buckets of 256 nodes

typedef unsigned short ushort;
typedef _Float16 f16;

__device__ __forceinline__ ushort f2h(float f) {  // v_cvt_f16_f32 (RNE)
  f16 h = (f16)f;
  return __builtin_bit_cast(ushort, h);
}
__device__ __forceinline__ float h2f(ushort u) {  // v_cvt_f32_f16
  f16 h = __builtin_bit_cast(f16, u);
  return (float)h;
}

// XCD-confined swizzle: block b -> XCD (b&7), 2 XCDs per graph.
// Requires G*N/4 = 50000 blocks; per graph 12500 chunks of 4 nodes.
__device__ __forceinline__ void xcd_map(int b, int& g, int& chunk) {
  int xcd = b & 7;
  int sub = b >> 3;  // 0..6249
  g = xcd >> 1;
  chunk = (xcd & 1) * 6250 + sub;  // 0..12499
}

// ---------------- fp32 -> fp16 conversion of x, PRE-SCALED by dinv ----------------
// R7: fp16 halves gather bytes + L2 working set. R10: also fold dinv[s] into
// the stored row (xh[s] = dinv[s]*x[s]) so the aggregation needs NO per-edge
// dinv gather -- Z = dinv[d] * sum_{s in N(d)+self} xh[s]. Runs AFTER the scans.
__global__ void k_x2h(const float4* __restrict__ X, const float* __restrict__ dinv,
                      ushort4* __restrict__ Xh, int n4) {
  int i = blockIdx.x * blockDim.x + threadIdx.x;
  if (i >= n4) return;
  float sc = dinv[i >> 4];  // 16 float4 per 64-wide row; same dinv for all 16
  float4 v = X[i];
  ushort4 o = {f2h(sc * v.x), f2h(sc * v.y), f2h(sc * v.z), f2h(sc * v.w)};
  Xh[i] = o;
}

// ---------------- CSR build: two-pass radix partition by dst (R9) ----------------
// R8 post-mortem: scattered SUB-LINE stores cost like atomics (8x write amp).
// All global writes made (near-)line-contiguous via 196-bucket dst partition.

// PH[g][k][pb]: bucket-k count of partition chunk pb
__global__ __launch_bounds__(256) void k_phist(const int* __restrict__ ei,
                                               int* __restrict__ PH) {
  __shared__ int h[NBK];
  int pb = blockIdx.x, g = blockIdx.y;
  for (int i = threadIdx.x; i < NBK; i += 256) h[i] = 0;
  __syncthreads();
  const int4* dst4 = (const int4*)(ei + (size_t)g * 2 * E + E + (size_t)pb * CP);
  for (int i = threadIdx.x; i < CP / 4; i += 256) {
    int4 d = dst4[i];
    atomicAdd(&h[d.x >> 8], 1);
    atomicAdd(&h[d.y >> 8], 1);
    atomicAdd(&h[d.z >> 8], 1);
    atomicAdd(&h[d.w >> 8], 1);
  }
  __syncthreads();
  for (int i = threadIdx.x; i < NBK; i += 256)
    PH[((size_t)g * NBK + i) * PB + pb] = h[i];
}

// scan PH -> POFF[g][k][pb] (segment base in pairs) and BB[g][k] (bucket base)
__global__ void k_pscan(const int* __restrict__ PH, int* __restrict__ POFF,
                        int* __restrict__ BB) {
  int g = blockIdx.x, k = threadIdx.x;  // 256 threads, k < NBK active
  int tot = 0;
  if (k < NBK) {
#pragma unroll 8
    for (int pb = 0; pb < PB; ++pb) tot += PH[((size_t)g * NBK + k) * PB + pb];
  }
  __shared__ int sm[256];
  sm[k] = tot;
  __syncthreads();
  for (int off = 1; off < 256; off <<= 1) {
    int v = (k >= off) ? sm[k - off] : 0;
    __syncthreads();
    sm[k] += v;
    __syncthreads();
  }
  int excl = sm[k] - tot;
  if (k < NBK) {
    BB[g * (NBK + 1) + k] = excl;
    if (k == NBK - 1) BB[g * (NBK + 1) + NBK] = excl + tot;  // == E
    int run = excl;
#pragma unroll 8
    for (int pb = 0; pb < PB; ++pb) {
      POFF[((size_t)g * NBK + k) * PB + pb] = run;
      run += PH[((size_t)g * NBK + k) * PB + pb];
    }
  }
}

// partition: write packed (src, dst&255) into bucket-major pairs array
__global__ __launch_bounds__(256) void k_part(const int* __restrict__ ei,
                                              const int* __restrict__ POFF,
                                              unsigned* __restrict__ pairs) {
  __shared__ int off[NBK];
  __shared__ int rk[NBK];
  int pb = blockIdx.x, g = blockIdx.y;
  for (int i = threadIdx.x; i < NBK; i += 256) {
    off[i] = POFF[((size_t)g * NBK + i) * PB + pb];
    rk[i] = 0;
  }
  __syncthreads();
  const int* base = ei + (size_t)g * 2 * E + (size_t)pb * CP;
  const int4* s4 = (const int4*)base;
  const int4* d4 = (const int4*)(base + E);
  unsigned* pg = pairs + (size_t)g * E;
  for (int i = threadIdx.x; i < CP / 4; i += 256) {
    int4 s = s4[i], d = d4[i];
    int sv[4] = {s.x, s.y, s.z, s.w};
    int dv[4] = {d.x, d.y, d.z, d.w};
#pragma unroll
    for (int k = 0; k < 4; ++k) {
      int b = dv[k] >> 8;
      int r = atomicAdd(&rk[b], 1);
      pg[off[b] + r] = (unsigned)sv[k] | ((unsigned)(dv[k] & 255) << 16);
    }
  }
}

// per-bucket exact node counts -> cnt (contiguous writes)
__global__ __launch_bounds__(256) void k_bcnt(const unsigned* __restrict__ pairs,
                                              const int* __restrict__ BB,
                                              int* __restrict__ cnt) {
  __shared__ int h[256];
  int k = blockIdx.x, g = blockIdx.y;
  h[threadIdx.x] = 0;
  __syncthreads();
  int lo = BB[g * (NBK + 1) + k], hi = BB[g * (NBK + 1) + k + 1];
  const unsigned* pg = pairs + (size_t)g * E;
  for (int i = lo + (int)threadIdx.x; i < hi; i += 256)
    atomicAdd(&h[(pg[i] >> 16) & 255], 1);
  __syncthreads();
  int n0 = k << 8;
  int nn = min(256, N - n0);
  if ((int)threadIdx.x < nn) cnt[g * N + n0 + threadIdx.x] = h[threadIdx.x];
}

// place srcs into col; scatter confined to the bucket's ~16KB col window
__global__ __launch_bounds__(256) void k_place(const unsigned* __restrict__ pairs,
                                               const int* __restrict__ BB,
                                               const int* __restrict__ rowptr,
                                               int* __restrict__ col) {
  __shared__ int rp[256];
  __shared__ int rk[256];
  int k = blockIdx.x, g = blockIdx.y;
  int n0 = k << 8;
  int nn = min(256, N - n0);
  if ((int)threadIdx.x < nn) rp[threadIdx.x] = rowptr[g * (N + 1) + n0 + threadIdx.x];
  rk[threadIdx.x] = 0;
  __syncthreads();
  int lo = BB[g * (NBK + 1) + k], hi = BB[g * (NBK + 1) + k + 1];
  const unsigned* pg = pairs + (size_t)g * E;
  int* cg = col + (size_t)g * E;
  for (int i = lo + (int)threadIdx.x; i < hi; i += 256) {
    unsigned p = pg[i];
    int dl = (p >> 16) & 255;
    int r = atomicAdd(&rk[dl], 1);
    cg[rp[dl] + r] = (int)(p & 0xffffu);
  }
}

// ---- 3-kernel exclusive scan of cnt -> rowptr (per graph) ----
__global__ void k_scan_partial(const int* __restrict__ cnt, int* __restrict__ part) {
  int g = blockIdx.y, b = blockIdx.x, tid = threadIdx.x;
  int base = b * 1024 + tid * 4;
  int s = 0;
#pragma unroll
  for (int k = 0; k < 4; ++k) {
    int i = base + k;
    if (i < N) s += cnt[g * N + i];
  }
  __shared__ int sm[256];
  sm[tid] = s;
  __syncthreads();
  for (int off = 128; off > 0; off >>= 1) {
    if (tid < off) sm[tid] += sm[tid + off];
    __syncthreads();
  }
  if (tid == 0) part[g * NB + b] = sm[0];
}

__global__ void k_scan_mid(int* __restrict__ part, int* __restrict__ rowptr) {
  int g = blockIdx.x;
  if (threadIdx.x != 0) return;
  int run = 0;
  for (int b = 0; b < NB; ++b) {
    int t = part[g * NB + b];
    part[g * NB + b] = run;
    run += t;
  }
  rowptr[g * (N + 1) + N] = run;  // == E
}

// final scan + fused dinv computation
__global__ void k_scan_final(const int* __restrict__ cnt, const int* __restrict__ part,
                             int* __restrict__ rowptr, float* __restrict__ dinv) {
  int g = blockIdx.y, b = blockIdx.x, tid = threadIdx.x;
  int base = b * 1024 + tid * 4;
  int c[4];
  int s = 0;
#pragma unroll
  for (int k = 0; k < 4; ++k) {
    int i = base + k;
    c[k] = (i < N) ? cnt[g * N + i] : 0;
    s += c[k];
  }
  __shared__ int sm[256];
  sm[tid] = s;
  __syncthreads();
  for (int off = 1; off < 256; off <<= 1) {
    int v = (tid >= off) ? sm[tid - off] : 0;
    __syncthreads();
    sm[tid] += v;
    __syncthreads();
  }
  int excl = sm[tid] - s + part[g * NB + b];
#pragma unroll
  for (int k = 0; k < 4; ++k) {
    int i = base + k;
    if (i < N) {
      rowptr[g * (N + 1) + i] = excl;
      dinv[g * N + i] = rsqrtf((float)(c[k] + 1));  // +1 self loop
    }
    excl += c[k];
  }
}

// ---------------- LDS-staged GEMM: columns across waves, lane = row ----------------
// Block = 256 threads = 4 waves, covers 64 rows. X tile staged ONCE in LDS
// (padded row stride K+1 -> (lane+k)%32 bank map, 2 lanes/bank = free).
// Wave w computes columns [w*F/4, (w+1)*F/4) for all 64 rows.
// c0 forced into an SGPR via readfirstlane so the W address chain is provably
// scalar -> batched s_load through the constant cache on the scalar pipe
// (R5 bug: threadIdx-derived c0 failed divergence analysis -> per-lane
// global_load_dword, VMEM-issue bound, 230 us).
template <int K, int F, bool PRESCALE, bool BIASELU, bool OUTH>
__global__ __launch_bounds__(256) void k_gemm_lds(const float* __restrict__ X,
                                                  const float* __restrict__ W,
                                                  const float* __restrict__ dinv,
                                                  const float* __restrict__ bias,
                                                  void* __restrict__ Hout) {
  constexpr int CH = F / 4;  // columns per wave (32 or 16)
  constexpr int PK = K + 1;  // padded LDS row stride
  __shared__ float xs[64 * PK];
  int g = blockIdx.y;
  int R0 = blockIdx.x * 64;
  // stage 64 rows (coalesced global read, conflict-free LDS write)
  for (int idx = threadIdx.x; idx < 64 * K; idx += 256) {
    int r = idx / K, k = idx - r * K;
    int row = R0 + r;
    xs[r * PK + k] = (row < N) ? X[((size_t)g * N + row) * K + k] : 0.f;
  }
  __syncthreads();
  int wv = threadIdx.x >> 6;
  int lane = threadIdx.x & 63;
  int c0 = __builtin_amdgcn_readfirstlane(wv * CH);  // SGPR column base
  const float* Wg = W + (size_t)g * K * F;
  const float* xrow = &xs[lane * PK];
  float acc[CH];
#pragma unroll
  for (int c = 0; c < CH; ++c) acc[c] = 0.f;
#pragma unroll 4
  for (int k = 0; k < K; ++k) {
    float xv = xrow[k];
#pragma unroll
    for (int c = 0; c < CH; ++c)
      acc[c] = fmaf(xv, Wg[(size_t)k * F + c0 + c], acc[c]);
  }
  int row = R0 + lane;
  if (row >= N) return;
  if constexpr (PRESCALE) {
    float sc = dinv[g * N + row];
#pragma unroll
    for (int c = 0; c < CH; ++c) acc[c] *= sc;
  }
  if constexpr (BIASELU) {
#pragma unroll
    for (int c = 0; c < CH; ++c) {
      float v = acc[c] + bias[g * F + c0 + c];
      acc[c] = v > 0.f ? v : expm1f(v);
    }
  }
  if constexpr (OUTH) {  // fp16 out (4x finer mantissa than bf16, same bytes)
    ushort* opb = (ushort*)Hout + ((size_t)g * N + row) * F + c0;
#pragma unroll
    for (int c4 = 0; c4 < CH; c4 += 4) {
      ushort4 o = {f2h(acc[c4]), f2h(acc[c4 + 1]), f2h(acc[c4 + 2]),
                   f2h(acc[c4 + 3])};
      *(ushort4*)(opb + c4) = o;
    }
  } else {
    float* op = (float*)Hout + ((size_t)g * N + row) * F + c0;
#pragma unroll
    for (int c4 = 0; c4 < CH; c4 += 4) {
      float4 o = {acc[c4], acc[c4 + 1], acc[c4 + 2], acc[c4 + 3]};
      *(float4*)(op + c4) = o;
    }
  }
}

// ---------------- aggregate core (R12) ----------------
// R11 post-mortem: quarter-wave ushort4 gathers REGRESSED (+35us) -- kernel was
// never VMEM-issue bound (issue util ~6%); the shfl epilogue added 17.9M LDS
// bank-conflict cycles and the select trees doubled VALU. Reverted to R10's
// scalar-index structure. R10's real limit was latency-parallelism: 8-deep
// batches = 23 in-flight/CU = exactly Little's-law demand at ~410cy avg gather
// latency -> waves stall on vmcnt. R12: 16-deep primary batch (2x in-flight),
// 8-deep secondary, scalar tail. No shuffles, no LDS.
__device__ __forceinline__ float agg_row(const ushort* __restrict__ hb,
                                         const int* __restrict__ cl, int rs, int re,
                                         int lane, float acc) {
  int j = rs;
  for (; j + 16 <= re; j += 16) {
    int s[16];
#pragma unroll
    for (int k = 0; k < 16; ++k) s[k] = cl[j + k];  // uniform -> s_load x16
    float v[16];
#pragma unroll
    for (int k = 0; k < 16; ++k) v[k] = h2f(hb[(size_t)s[k] * 64 + lane]);
#pragma unroll
    for (int k = 0; k < 16; ++k) acc += v[k];
  }
  for (; j + 8 <= re; j += 8) {
    int s[8];
#pragma unroll
    for (int k = 0; k < 8; ++k) s[k] = cl[j + k];
    float v[8];
#pragma unroll
    for (int k = 0; k < 8; ++k) v[k] = h2f(hb[(size_t)s[k] * 64 + lane]);
#pragma unroll
    for (int k = 0; k < 8; ++k) acc += v[k];
  }
  for (; j < re; ++j) acc += h2f(hb[(size_t)cl[j] * 64 + lane]);
  return acc;
}

// layer 1: Z = dinv[d] * sum xh[s] (xh pre-scaled by dinv[s])
template <int F>
__global__ __launch_bounds__(256) void k_agg_in(const ushort* __restrict__ Xh,
                                                const int* __restrict__ rowptr,
                                                const int* __restrict__ col,
                                                const float* __restrict__ dinv,
                                                float* __restrict__ Z) {
  int g, chunk;
  xcd_map(blockIdx.x, g, chunk);
  int d = __builtin_amdgcn_readfirstlane(chunk * 4 + (threadIdx.x >> 6));
  int lane = threadIdx.x & 63;
  const ushort* hb = Xh + (size_t)g * N * F;
  const int* cl = col + (size_t)g * E;
  int rs = rowptr[g * (N + 1) + d];
  int re = rowptr[g * (N + 1) + d + 1];
  float acc = h2f(hb[(size_t)d * F + lane]);  // self loop (pre-scaled row)
  acc = agg_row(hb, cl, rs, re, lane, acc);
  Z[((size_t)g * N + d) * F + lane] = dinv[g * N + d] * acc;
}

// layer 2: out = ELU(dinv[d]*(sum h2s) + b); h2s pre-scaled by dinv[s]
template <int F>
__global__ __launch_bounds__(256) void k_agg_out(const ushort* __restrict__ Hsrc,
                                                 const int* __restrict__ rowptr,
                                                 const int* __restrict__ col,
                                                 const float* __restrict__ dinv,
                                                 const float* __restrict__ bias,
                                                 float* __restrict__ out) {
  int g, chunk;
  xcd_map(blockIdx.x, g, chunk);
  int d = __builtin_amdgcn_readfirstlane(chunk * 4 + (threadIdx.x >> 6));
  int lane = threadIdx.x & 63;
  const ushort* hb = Hsrc + (size_t)g * N * F;
  const int* cl = col + (size_t)g * E;
  int rs = rowptr[g * (N + 1) + d];
  int re = rowptr[g * (N + 1) + d + 1];
  float acc = h2f(hb[(size_t)d * F + lane]);  // self loop
  acc = agg_row(hb, cl, rs, re, lane, acc);
  float p = acc * dinv[g * N + d] + bias[g * F + lane];
  p = p > 0.f ? p : expm1f(p);
  out[((size_t)g * N + d) * F + lane] = p;
}

extern "C" void kernel_launch(void* const* d_in, const int* in_sizes, int n_in,
                              void* d_out, int out_size, void* d_ws, size_t ws_size,
                              hipStream_t stream) {
  const float* x = (const float*)d_in[0];
  const int* ei = (const int*)d_in[1];
  const float* W1 = (const float*)d_in[2];
  const float* b1 = (const float*)d_in[3];
  const float* W2 = (const float*)d_in[4];
  const float* b2 = (const float*)d_in[5];
  float* out = (float*)d_out;

  // Workspace carve-up (~169 MB; all radix/fp16 scratch aliased onto h1)
  char* p = (char*)d_ws;
  auto alloc = [&](size_t bytes) {
    char* r = p;
    p += (bytes + 255) & ~(size_t)255;
    return r;
  };
  int* cnt = (int*)alloc(sizeof(int) * G * N);
  int* rowptr = (int*)alloc(sizeof(int) * G * (N + 1));
  int* part = (int*)alloc(sizeof(int) * G * NB);
  float* dinv = (float*)alloc(sizeof(float) * G * N);
  int* col = (int*)alloc(sizeof(int) * (size_t)G * E);             // 12.8 MB
  float* z = (float*)alloc(sizeof(float) * (size_t)G * N * FIN);   // 51.2 MB
  float* h1 = (float*)alloc(sizeof(float) * (size_t)G * N * HID);  // 102.4 MB
  ushort* h2s = (ushort*)z;  // fp16, 25.6 MB; reuses z (dead after gemm1)
  // Radix + fp16-x scratch aliased into h1 (all dead before gemm1 writes h1):
  unsigned* pairs = (unsigned*)h1;                         // 12.8 MB
  int* PH = (int*)((char*)h1 + ((size_t)13 << 20));        // G*NBK*PB*4 = 200KB
  int* POFF = (int*)((char*)h1 + ((size_t)14 << 20));      // 200KB
  int* BB = (int*)((char*)h1 + ((size_t)15 << 20));        // G*(NBK+1)*4 = 3.2KB
  ushort* xh = (ushort*)((char*)h1 + ((size_t)32 << 20));  // fp16 x, 25.6 MB

  // 1. CSR build via two-pass radix partition (line-contiguous writes only)
  k_phist<<<dim3(PB, G), 256, 0, stream>>>(ei, PH);
  k_pscan<<<G, 256, 0, stream>>>(PH, POFF, BB);
  k_part<<<dim3(PB, G), 256, 0, stream>>>(ei, POFF, pairs);
  k_bcnt<<<dim3(NBK, G), 256, 0, stream>>>(pairs, BB, cnt);
  dim3 sg(NB, G);
  k_scan_partial<<<sg, 256, 0, stream>>>(cnt, part);
  k_scan_mid<<<G, 64, 0, stream>>>(part, rowptr);
  k_scan_final<<<sg, 256, 0, stream>>>(cnt, part, rowptr, dinv);
  k_place<<<dim3(NBK, G), 256, 0, stream>>>(pairs, BB, rowptr, col);

  // 2. x -> fp16 pre-scaled by dinv (after scans; removes per-edge dinv work)
  k_x2h<<<(G * N * FIN / 4 + 255) / 256, 256, 0, stream>>>(
      (const float4*)x, dinv, (ushort4*)xh, G * N * FIN / 4);

  // 3. layer 1: aggregate-first (16-deep scalar-index fp16 gathers), then GEMM
  k_agg_in<FIN><<<(G * N) / 4, 256, 0, stream>>>(xh, rowptr, col, dinv, z);
  dim3 gg((N + 63) / 64, G);
  k_gemm_lds<FIN, HID, false, true, false>
      <<<gg, 256, 0, stream>>>(z, W1, nullptr, b1, h1);

  // 4. layer 2: transform-first 128->64 (pre-scaled, fp16 out), then aggregate
  k_gemm_lds<HID, FOUT, true, false, true>
      <<<gg, 256, 0, stream>>>(h1, W2, dinv, nullptr, h2s);
  k_agg_out<FOUT><<<(G * N) / 4, 256, 0, stream>>>(h2s, rowptr, col, dinv, b2, out);
}

// Round 9
// 483.451 us; speedup vs baseline: 1.1307x; 1.0690x over previous
//
#include <hip/hip_runtime.h>
#include <cstdint>

// Problem constants (from reference)
constexpr int G = 4, N = 50000, E = 800000;
constexpr int FIN = 64, HID = 128, FOUT = 64;
constexpr int NB = (N + 1023) / 1024;  // scan blocks per graph = 49

// Radix CSR-build parameters (R9)
constexpr int PB = 64;               // partition blocks per graph
constexpr int CP = E / PB;           // 12500 edges per partition chunk (exact)
constexpr int NBK = (N + 255) / 256; // 196 dst-buckets of 256 nodes

typedef unsigned short ushort;
typedef _Float16 f16;

__device__ __forceinline__ ushort f2h(float f) {  // v_cvt_f16_f32 (RNE)
  f16 h = (f16)f;
  return __builtin_bit_cast(ushort, h);
}
__device__ __forceinline__ float h2f(ushort u) {  // v_cvt_f32_f16
  f16 h = __builtin_bit_cast(f16, u);
  return (float)h;
}

// XCD-confined swizzle: block b -> XCD (b&7), 2 XCDs per graph.
// Requires G*N/4 = 50000 blocks; per graph 12500 chunks of 4 nodes.
__device__ __forceinline__ void xcd_map(int b, int& g, int& chunk) {
  int xcd = b & 7;
  int sub = b >> 3;  // 0..6249
  g = xcd >> 1;
  chunk = (xcd & 1) * 6250 + sub;  // 0..12499
}

// ---------------- fp32 -> fp16 conversion of x, PRE-SCALED by dinv ----------------
// R7: fp16 halves gather bytes + L2 working set. R10: also fold dinv[s] into
// the stored row (xh[s] = dinv[s]*x[s]) so the aggregation needs NO per-edge
// dinv gather -- Z = dinv[d] * sum_{s in N(d)+self} xh[s]. Runs AFTER the scans.
__global__ void k_x2h(const float4* __restrict__ X, const float* __restrict__ dinv,
                      ushort4* __restrict__ Xh, int n4) {
  int i = blockIdx.x * blockDim.x + threadIdx.x;
  if (i >= n4) return;
  float sc = dinv[i >> 4];  // 16 float4 per 64-wide row; same dinv for all 16
  float4 v = X[i];
  ushort4 o = {f2h(sc * v.x), f2h(sc * v.y), f2h(sc * v.z), f2h(sc * v.w)};
  Xh[i] = o;
}

// ---------------- CSR build: two-pass radix partition by dst (R9) ----------------
// R8 post-mortem: scattered SUB-LINE stores cost like atomics (8x write amp).
// All global writes made (near-)line-contiguous via 196-bucket dst partition.

// PH[g][k][pb]: bucket-k count of partition chunk pb
__global__ __launch_bounds__(256) void k_phist(const int* __restrict__ ei,
                                               int* __restrict__ PH) {
  __shared__ int h[NBK];
  int pb = blockIdx.x, g = blockIdx.y;
  for (int i = threadIdx.x; i < NBK; i += 256) h[i] = 0;
  __syncthreads();
  const int4* dst4 = (const int4*)(ei + (size_t)g * 2 * E + E + (size_t)pb * CP);
  for (int i = threadIdx.x; i < CP / 4; i += 256) {
    int4 d = dst4[i];
    atomicAdd(&h[d.x >> 8], 1);
    atomicAdd(&h[d.y >> 8], 1);
    atomicAdd(&h[d.z >> 8], 1);
    atomicAdd(&h[d.w >> 8], 1);
  }
  __syncthreads();
  for (int i = threadIdx.x; i < NBK; i += 256)
    PH[((size_t)g * NBK + i) * PB + pb] = h[i];
}

// scan PH -> POFF[g][k][pb] (segment base in pairs) and BB[g][k] (bucket base)
__global__ void k_pscan(const int* __restrict__ PH, int* __restrict__ POFF,
                        int* __restrict__ BB) {
  int g = blockIdx.x, k = threadIdx.x;  // 256 threads, k < NBK active
  int tot = 0;
  if (k < NBK) {
#pragma unroll 8
    for (int pb = 0; pb < PB; ++pb) tot += PH[((size_t)g * NBK + k) * PB + pb];
  }
  __shared__ int sm[256];
  sm[k] = tot;
  __syncthreads();
  for (int off = 1; off < 256; off <<= 1) {
    int v = (k >= off) ? sm[k - off] : 0;
    __syncthreads();
    sm[k] += v;
    __syncthreads();
  }
  int excl = sm[k] - tot;
  if (k < NBK) {
    BB[g * (NBK + 1) + k] = excl;
    if (k == NBK - 1) BB[g * (NBK + 1) + NBK] = excl + tot;  // == E
    int run = excl;
#pragma unroll 8
    for (int pb = 0; pb < PB; ++pb) {
      POFF[((size_t)g * NBK + k) * PB + pb] = run;
      run += PH[((size_t)g * NBK + k) * PB + pb];
    }
  }
}

// partition: write packed (src, dst&255) into bucket-major pairs array
__global__ __launch_bounds__(256) void k_part(const int* __restrict__ ei,
                                              const int* __restrict__ POFF,
                                              unsigned* __restrict__ pairs) {
  __shared__ int off[NBK];
  __shared__ int rk[NBK];
  int pb = blockIdx.x, g = blockIdx.y;
  for (int i = threadIdx.x; i < NBK; i += 256) {
    off[i] = POFF[((size_t)g * NBK + i) * PB + pb];
    rk[i] = 0;
  }
  __syncthreads();
  const int* base = ei + (size_t)g * 2 * E + (size_t)pb * CP;
  const int4* s4 = (const int4*)base;
  const int4* d4 = (const int4*)(base + E);
  unsigned* pg = pairs + (size_t)g * E;
  for (int i = threadIdx.x; i < CP / 4; i += 256) {
    int4 s = s4[i], d = d4[i];
    int sv[4] = {s.x, s.y, s.z, s.w};
    int dv[4] = {d.x, d.y, d.z, d.w};
#pragma unroll
    for (int k = 0; k < 4; ++k) {
      int b = dv[k] >> 8;
      int r = atomicAdd(&rk[b], 1);
      pg[off[b] + r] = (unsigned)sv[k] | ((unsigned)(dv[k] & 255) << 16);
    }
  }
}

// per-bucket exact node counts -> cnt (contiguous writes)
__global__ __launch_bounds__(256) void k_bcnt(const unsigned* __restrict__ pairs,
                                              const int* __restrict__ BB,
                                              int* __restrict__ cnt) {
  __shared__ int h[256];
  int k = blockIdx.x, g = blockIdx.y;
  h[threadIdx.x] = 0;
  __syncthreads();
  int lo = BB[g * (NBK + 1) + k], hi = BB[g * (NBK + 1) + k + 1];
  const unsigned* pg = pairs + (size_t)g * E;
  for (int i = lo + (int)threadIdx.x; i < hi; i += 256)
    atomicAdd(&h[(pg[i] >> 16) & 255], 1);
  __syncthreads();
  int n0 = k << 8;
  int nn = min(256, N - n0);
  if ((int)threadIdx.x < nn) cnt[g * N + n0 + threadIdx.x] = h[threadIdx.x];
}

// place srcs into col; scatter confined to the bucket's ~16KB col window
__global__ __launch_bounds__(256) void k_place(const unsigned* __restrict__ pairs,
                                               const int* __restrict__ BB,
                                               const int* __restrict__ rowptr,
                                               int* __restrict__ col) {
  __shared__ int rp[256];
  __shared__ int rk[256];
  int k = blockIdx.x, g = blockIdx.y;
  int n0 = k << 8;
  int nn = min(256, N - n0);
  if ((int)threadIdx.x < nn) rp[threadIdx.x] = rowptr[g * (N + 1) + n0 + threadIdx.x];
  rk[threadIdx.x] = 0;
  __syncthreads();
  int lo = BB[g * (NBK + 1) + k], hi = BB[g * (NBK + 1) + k + 1];
  const unsigned* pg = pairs + (size_t)g * E;
  int* cg = col + (size_t)g * E;
  for (int i = lo + (int)threadIdx.x; i < hi; i += 256) {
    unsigned p = pg[i];
    int dl = (p >> 16) & 255;
    int r = atomicAdd(&rk[dl], 1);
    cg[rp[dl] + r] = (int)(p & 0xffffu);
  }
}

// ---- 3-kernel exclusive scan of cnt -> rowptr (per graph) ----
__global__ void k_scan_partial(const int* __restrict__ cnt, int* __restrict__ part) {
  int g = blockIdx.y, b = blockIdx.x, tid = threadIdx.x;
  int base = b * 1024 + tid * 4;
  int s = 0;
#pragma unroll
  for (int k = 0; k < 4; ++k) {
    int i = base + k;
    if (i < N) s += cnt[g * N + i];
  }
  __shared__ int sm[256];
  sm[tid] = s;
  __syncthreads();
  for (int off = 128; off > 0; off >>= 1) {
    if (tid < off) sm[tid] += sm[tid + off];
    __syncthreads();
  }
  if (tid == 0) part[g * NB + b] = sm[0];
}

__global__ void k_scan_mid(int* __restrict__ part, int* __restrict__ rowptr) {
  int g = blockIdx.x;
  if (threadIdx.x != 0) return;
  int run = 0;
  for (int b = 0; b < NB; ++b) {
    int t = part[g * NB + b];
    part[g * NB + b] = run;
    run += t;
  }
  rowptr[g * (N + 1) + N] = run;  // == E
}

// final scan + fused dinv computation
__global__ void k_scan_final(const int* __restrict__ cnt, const int* __restrict__ part,
                             int* __restrict__ rowptr, float* __restrict__ dinv) {
  int g = blockIdx.y, b = blockIdx.x, tid = threadIdx.x;
  int base = b * 1024 + tid * 4;
  int c[4];
  int s = 0;
#pragma unroll
  for (int k = 0; k < 4; ++k) {
    int i = base + k;
    c[k] = (i < N) ? cnt[g * N + i] : 0;
    s += c[k];
  }
  __shared__ int sm[256];
  sm[tid] = s;
  __syncthreads();
  for (int off = 1; off < 256; off <<= 1) {
    int v = (tid >= off) ? sm[tid - off] : 0;
    __syncthreads();
    sm[tid] += v;
    __syncthreads();
  }
  int excl = sm[tid] - s + part[g * NB + b];
#pragma unroll
  for (int k = 0; k < 4; ++k) {
    int i = base + k;
    if (i < N) {
      rowptr[g * (N + 1) + i] = excl;
      dinv[g * N + i] = rsqrtf((float)(c[k] + 1));  // +1 self loop
    }
    excl += c[k];
  }
}

// ---------------- fused MLP: h2s = dinv * (ELU(Z@W1 + b1) @ W2), fp16 out ----------------
// R13: gemm1 (z->h1, 89us-class) + gemm2 (h1->h2s, 89.6us) fused; h1 (102MB)
// never touches memory. Block = 256 thr = 4 waves over 64 rows (lane = row).
// Wave w holds gemm1 cols/k-slice [32w,32w+32) in acc[32] (bias+ELU applied ->
// these ARE h1 values). gemm2 sums over k: each wave computes partial
// h2[64x64] from its k-slice (2048 FMA -- exactly gemm2's FLOPs), partials
// combined in LDS [4][32][65] f32 (padded, conflict-free), in two 32-col
// phases to halve VGPR (acc[32]+ph[32] ~ 90 VGPR). W1/W2 addresses are
// scalar (readfirstlane c0) -> constant-cache s_load (R5 lesson).
__global__ __launch_bounds__(256) void k_mlp(const float* __restrict__ X,
                                             const float* __restrict__ W1,
                                             const float* __restrict__ b1,
                                             const float* __restrict__ W2,
                                             const float* __restrict__ dinv,
                                             ushort* __restrict__ H2s) {
  constexpr int K = FIN;    // 64
  constexpr int PK = K + 1; // padded LDS row stride for x tile
  __shared__ float lds[4 * 32 * 65];  // 33280B; aliased: x tile (4160 f) then partials
  float* xs = lds;
  int g = blockIdx.y;
  int R0 = blockIdx.x * 64;
  // stage 64 rows of Z (coalesced global read, conflict-free LDS write)
  for (int idx = threadIdx.x; idx < 64 * K; idx += 256) {
    int r = idx / K, k = idx - r * K;
    int row = R0 + r;
    xs[r * PK + k] = (row < N) ? X[((size_t)g * N + row) * K + k] : 0.f;
  }
  __syncthreads();
  int wv = threadIdx.x >> 6;
  int lane = threadIdx.x & 63;
  int c0 = __builtin_amdgcn_readfirstlane(wv * 32);  // SGPR col base (HID slice)
  const float* W1g = W1 + (size_t)g * K * HID;
  const float* xrow = &xs[lane * PK];
  float acc[32];
#pragma unroll
  for (int c = 0; c < 32; ++c) acc[c] = 0.f;
#pragma unroll 4
  for (int k = 0; k < K; ++k) {
    float xv = xrow[k];
#pragma unroll
    for (int c = 0; c < 32; ++c)
      acc[c] = fmaf(xv, W1g[(size_t)k * HID + c0 + c], acc[c]);
  }
  // bias + ELU -> acc = h1[row][c0..c0+31]
#pragma unroll
  for (int c = 0; c < 32; ++c) {
    float v = acc[c] + b1[g * HID + c0 + c];
    acc[c] = v > 0.f ? v : expm1f(v);
  }
  // gemm2 in two 32-col phases
  const float* W2g = W2 + (size_t)g * HID * FOUT;
  int rrow = threadIdx.x >> 2;        // reduce-phase mapping
  int jg = threadIdx.x & 3;
  for (int h = 0; h < 2; ++h) {
    float ph[32];
#pragma unroll
    for (int j = 0; j < 32; ++j) ph[j] = 0.f;
    for (int c = 0; c < 32; ++c) {  // scalar W2 row slice (s_load)
      const float* wr = &W2g[(size_t)(c0 + c) * FOUT + h * 32];
      float av = acc[c];
#pragma unroll
      for (int j = 0; j < 32; ++j) ph[j] = fmaf(av, wr[j], ph[j]);
    }
    __syncthreads();  // h=0: xs reads done; h=1: prev reduce reads done
#pragma unroll
    for (int j = 0; j < 32; ++j) lds[wv * 2080 + j * 65 + lane] = ph[j];
    __syncthreads();
    if (R0 + rrow < N) {
      float dd = dinv[g * N + R0 + rrow];
      ushort4 oa, ob;
      {
        int j = jg * 8;
        float s0 = lds[j * 65 + rrow] + lds[2080 + j * 65 + rrow] +
                   lds[4160 + j * 65 + rrow] + lds[6240 + j * 65 + rrow];
        float s1 = lds[(j + 1) * 65 + rrow] + lds[2080 + (j + 1) * 65 + rrow] +
                   lds[4160 + (j + 1) * 65 + rrow] + lds[6240 + (j + 1) * 65 + rrow];
        float s2 = lds[(j + 2) * 65 + rrow] + lds[2080 + (j + 2) * 65 + rrow] +
                   lds[4160 + (j + 2) * 65 + rrow] + lds[6240 + (j + 2) * 65 + rrow];
        float s3 = lds[(j + 3) * 65 + rrow] + lds[2080 + (j + 3) * 65 + rrow] +
                   lds[4160 + (j + 3) * 65 + rrow] + lds[6240 + (j + 3) * 65 + rrow];
        oa = {f2h(s0 * dd), f2h(s1 * dd), f2h(s2 * dd), f2h(s3 * dd)};
        float s4 = lds[(j + 4) * 65 + rrow] + lds[2080 + (j + 4) * 65 + rrow] +
                   lds[4160 + (j + 4) * 65 + rrow] + lds[6240 + (j + 4) * 65 + rrow];
        float s5 = lds[(j + 5) * 65 + rrow] + lds[2080 + (j + 5) * 65 + rrow] +
                   lds[4160 + (j + 5) * 65 + rrow] + lds[6240 + (j + 5) * 65 + rrow];
        float s6 = lds[(j + 6) * 65 + rrow] + lds[2080 + (j + 6) * 65 + rrow] +
                   lds[4160 + (j + 6) * 65 + rrow] + lds[6240 + (j + 6) * 65 + rrow];
        float s7 = lds[(j + 7) * 65 + rrow] + lds[2080 + (j + 7) * 65 + rrow] +
                   lds[4160 + (j + 7) * 65 + rrow] + lds[6240 + (j + 7) * 65 + rrow];
        ob = {f2h(s4 * dd), f2h(s5 * dd), f2h(s6 * dd), f2h(s7 * dd)};
      }
      ushort* dst = H2s + ((size_t)g * N + R0 + rrow) * FOUT + h * 32 + jg * 8;
      *(ushort4*)dst = oa;
      *(ushort4*)(dst + 4) = ob;
    }
  }
}

// ---------------- aggregate core (R12) ----------------
// R11 post-mortem: quarter-wave ushort4 gathers REGRESSED -- shfl epilogue
// added 17.9M LDS bank-conflict cycles. R12: R10 scalar-index structure,
// 16-deep primary batch, 8-deep secondary, scalar tail. ~89us floor = TA/
// line-processing bound (2 lines per 128B row-gather), invariant to MLP.
__device__ __forceinline__ float agg_row(const ushort* __restrict__ hb,
                                         const int* __restrict__ cl, int rs, int re,
                                         int lane, float acc) {
  int j = rs;
  for (; j + 16 <= re; j += 16) {
    int s[16];
#pragma unroll
    for (int k = 0; k < 16; ++k) s[k] = cl[j + k];  // uniform -> s_load x16
    float v[16];
#pragma unroll
    for (int k = 0; k < 16; ++k) v[k] = h2f(hb[(size_t)s[k] * 64 + lane]);
#pragma unroll
    for (int k = 0; k < 16; ++k) acc += v[k];
  }
  for (; j + 8 <= re; j += 8) {
    int s[8];
#pragma unroll
    for (int k = 0; k < 8; ++k) s[k] = cl[j + k];
    float v[8];
#pragma unroll
    for (int k = 0; k < 8; ++k) v[k] = h2f(hb[(size_t)s[k] * 64 + lane]);
#pragma unroll
    for (int k = 0; k < 8; ++k) acc += v[k];
  }
  for (; j < re; ++j) acc += h2f(hb[(size_t)cl[j] * 64 + lane]);
  return acc;
}

// layer 1: Z = dinv[d] * sum xh[s] (xh pre-scaled by dinv[s])
template <int F>
__global__ __launch_bounds__(256) void k_agg_in(const ushort* __restrict__ Xh,
                                                const int* __restrict__ rowptr,
                                                const int* __restrict__ col,
                                                const float* __restrict__ dinv,
                                                float* __restrict__ Z) {
  int g, chunk;
  xcd_map(blockIdx.x, g, chunk);
  int d = __builtin_amdgcn_readfirstlane(chunk * 4 + (threadIdx.x >> 6));
  int lane = threadIdx.x & 63;
  const ushort* hb = Xh + (size_t)g * N * F;
  const int* cl = col + (size_t)g * E;
  int rs = rowptr[g * (N + 1) + d];
  int re = rowptr[g * (N + 1) + d + 1];
  float acc = h2f(hb[(size_t)d * F + lane]);  // self loop (pre-scaled row)
  acc = agg_row(hb, cl, rs, re, lane, acc);
  Z[((size_t)g * N + d) * F + lane] = dinv[g * N + d] * acc;
}

// layer 2: out = ELU(dinv[d]*(sum h2s) + b); h2s pre-scaled by dinv[s]
template <int F>
__global__ __launch_bounds__(256) void k_agg_out(const ushort* __restrict__ Hsrc,
                                                 const int* __restrict__ rowptr,
                                                 const int* __restrict__ col,
                                                 const float* __restrict__ dinv,
                                                 const float* __restrict__ bias,
                                                 float* __restrict__ out) {
  int g, chunk;
  xcd_map(blockIdx.x, g, chunk);
  int d = __builtin_amdgcn_readfirstlane(chunk * 4 + (threadIdx.x >> 6));
  int lane = threadIdx.x & 63;
  const ushort* hb = Hsrc + (size_t)g * N * F;
  const int* cl = col + (size_t)g * E;
  int rs = rowptr[g * (N + 1) + d];
  int re = rowptr[g * (N + 1) + d + 1];
  float acc = h2f(hb[(size_t)d * F + lane]);  // self loop
  acc = agg_row(hb, cl, rs, re, lane, acc);
  float p = acc * dinv[g * N + d] + bias[g * F + lane];
  p = p > 0.f ? p : expm1f(p);
  out[((size_t)g * N + d) * F + lane] = p;
}

extern "C" void kernel_launch(void* const* d_in, const int* in_sizes, int n_in,
                              void* d_out, int out_size, void* d_ws, size_t ws_size,
                              hipStream_t stream) {
  const float* x = (const float*)d_in[0];
  const int* ei = (const int*)d_in[1];
  const float* W1 = (const float*)d_in[2];
  const float* b1 = (const float*)d_in[3];
  const float* W2 = (const float*)d_in[4];
  const float* b2 = (const float*)d_in[5];
  float* out = (float*)d_out;

  // Workspace carve-up (layout kept from R9; h1's region now only holds the
  // radix + fp16-x scratch -- h1 itself no longer exists, R13 fused it away)
  char* p = (char*)d_ws;
  auto alloc = [&](size_t bytes) {
    char* r = p;
    p += (bytes + 255) & ~(size_t)255;
    return r;
  };
  int* cnt = (int*)alloc(sizeof(int) * G * N);
  int* rowptr = (int*)alloc(sizeof(int) * G * (N + 1));
  int* part = (int*)alloc(sizeof(int) * G * NB);
  float* dinv = (float*)alloc(sizeof(float) * G * N);
  int* col = (int*)alloc(sizeof(int) * (size_t)G * E);             // 12.8 MB
  float* z = (float*)alloc(sizeof(float) * (size_t)G * N * FIN);   // 51.2 MB
  char* scratch = (char*)alloc((size_t)103 << 20);                 // ex-h1 region
  ushort* h2s = (ushort*)z;  // fp16, 25.6 MB; reuses z (dead after k_mlp reads it)
  unsigned* pairs = (unsigned*)scratch;                    // 12.8 MB
  int* PH = (int*)(scratch + ((size_t)13 << 20));          // G*NBK*PB*4 = 200KB
  int* POFF = (int*)(scratch + ((size_t)14 << 20));        // 200KB
  int* BB = (int*)(scratch + ((size_t)15 << 20));          // G*(NBK+1)*4 = 3.2KB
  ushort* xh = (ushort*)(scratch + ((size_t)32 << 20));    // fp16 x, 25.6 MB

  // 1. CSR build via two-pass radix partition (line-contiguous writes only)
  k_phist<<<dim3(PB, G), 256, 0, stream>>>(ei, PH);
  k_pscan<<<G, 256, 0, stream>>>(PH, POFF, BB);
  k_part<<<dim3(PB, G), 256, 0, stream>>>(ei, POFF, pairs);
  k_bcnt<<<dim3(NBK, G), 256, 0, stream>>>(pairs, BB, cnt);
  dim3 sg(NB, G);
  k_scan_partial<<<sg, 256, 0, stream>>>(cnt, part);
  k_scan_mid<<<G, 64, 0, stream>>>(part, rowptr);
  k_scan_final<<<sg, 256, 0, stream>>>(cnt, part, rowptr, dinv);
  k_place<<<dim3(NBK, G), 256, 0, stream>>>(pairs, BB, rowptr, col);

  // 2. x -> fp16 pre-scaled by dinv (after scans; removes per-edge dinv work)
  k_x2h<<<(G * N * FIN / 4 + 255) / 256, 256, 0, stream>>>(
      (const float4*)x, dinv, (ushort4*)xh, G * N * FIN / 4);

  // 3. layer 1 aggregate (16-deep scalar-index fp16 gathers)
  k_agg_in<FIN><<<(G * N) / 4, 256, 0, stream>>>(xh, rowptr, col, dinv, z);

  // 4. fused MLP: z -> (h1 in-register) -> h2s (pre-scaled fp16)
  dim3 gg((N + 63) / 64, G);
  k_mlp<<<gg, 256, 0, stream>>>(z, W1, b1, W2, dinv, h2s);

  // 5. layer 2 aggregate + bias + ELU
  k_agg_out<FOUT><<<(G * N) / 4, 256, 0, stream>>>(h2s, rowptr, col, dinv, b2, out);
}